// Round 21
// baseline (67.489 us; speedup 1.0000x reference)
//
#pragma clang fp contract(off)
#include <hip/hip_runtime.h>
#include <math.h>

#define G       104
#define NBA     9
#define NC      80
#define NBOX    (G*G*NBA)      // 97344
#define CH      (5+NC)         // 85
#define DET_T_  0.02f
#define NMS_T_  0.3f
#define MAXB    50
#define SORTN   2048
#define IMG     832
#define DB      128            // decode boxes per block
#define NDB     ((NBOX + DB - 1) / DB)   // 761 decode blocks

typedef unsigned long long u64;
typedef unsigned int       u32;

__device__ __forceinline__ float sigmoidf_(float x) { return 1.0f / (1.0f + expf(-x)); }

// ---------------- decode: per-BLOCK deterministic class buckets (R20-proven) ----------------
// key = score_bits<<32 | ~id  (u64 desc == score desc, tie -> min original id)
__global__ __launch_bounds__(DB) void decode_kernel(const float* __restrict__ in,
        const float* __restrict__ anchors, u32* __restrict__ bcnt, u32* __restrict__ boff,
        u64* __restrict__ bkey, float4* __restrict__ boxById, float4* __restrict__ out4)
{
    __shared__ float lds[DB * CH];   // 43,520 B
    __shared__ u32   lcnt[NC], loff[NC];
    const int tid = threadIdx.x;
    const int b   = blockIdx.x;

    // canvas zero slice (stream-ordered before select_draw)
    {
        const int CZ = (IMG*IMG/4 + NDB - 1) / NDB;   // 228 float4 per block
        int zbase = b * CZ;
        for (int i = tid; i < CZ; i += DB) {
            int idx = zbase + i;
            if (idx < IMG*IMG/4) out4[idx] = make_float4(0, 0, 0, 0);
        }
    }

    const int base = b * (DB * CH);
    int nfl = NBOX * CH - base;
    if (nfl > DB * CH) nfl = DB * CH;

    int nv4 = nfl >> 2;
    const float4* gin4 = (const float4*)(in + base);
    for (int i = tid; i < nv4; i += DB) ((float4*)lds)[i] = gin4[i];
    for (int i = (nv4 << 2) + tid; i < nfl; i += DB) lds[i] = in[base + i];
    if (tid < NC) lcnt[tid] = 0;
    __syncthreads();

    int n = b * DB + tid;
    bool det = false; u64 key = 0; int bcls = 0; u32 rank = 0;

    if (n < NBOX) {
        const float* p = lds + tid * CH;

        float m = -INFINITY;
#pragma unroll
        for (int i = 0; i < NC; ++i) m = fmaxf(m, p[5 + i]);

        // sum in reference order + candidate bitmask (window -2e-6, 5x margin)
        float sum = 0.0f;
        u64 cm0 = 0, cm1 = 0;
#pragma unroll
        for (int i = 0; i < NC; ++i) {
            float d = p[5 + i] - m;
            sum += expf(d);
            u64 cand = (d >= -2.0e-6f) ? 1ull : 0ull;
            if (i < 64) cm0 |= cand << i;
            else        cm1 |= cand << (i - 64);
        }
        float obj = sigmoidf_(p[4]);

        // exact first-max over candidate classes only (ascending index)
        float best = -1.0f;
        while (cm0) {
            int i = __ffsll((long long)cm0) - 1; cm0 &= cm0 - 1;
            float e = expf(p[5 + i] - m);
            float s = obj * (e / sum);
            if (s > best) { best = s; bcls = i; }
        }
        while (cm1) {
            int i = __ffsll((long long)cm1) - 1 + 64; cm1 &= cm1 - 1;
            float e = expf(p[5 + i] - m);
            float s = obj * (e / sum);
            if (s > best) { best = s; bcls = i; }
        }

        if (best > DET_T_) {
            int a  = n % NBA;
            int t2 = n / NBA;
            int gx = t2 % G;
            int gy = t2 / G;
            float bx = (sigmoidf_(p[0]) + (float)gx) / (float)G;
            float by = (sigmoidf_(p[1]) + (float)gy) / (float)G;
            float bw = expf(p[2]) * anchors[2*a + 0] / (float)G;
            float bh = expf(p[3]) * anchors[2*a + 1] / (float)G;
            boxById[n] = make_float4(bx - bw / 2.0f, by - bh / 2.0f,
                                     bx + bw / 2.0f, by + bh / 2.0f);
            key = ((u64)__float_as_uint(best) << 32) | (u32)(~(u32)n);
            det = true;
        }
    }

    if (det) rank = atomicAdd(&lcnt[bcls], 1);    // rank within (block, class)
    __syncthreads();
    if (tid == 0) {                                // exclusive prefix over 80 classes
        u32 acc = 0;
        for (int c2 = 0; c2 < NC; ++c2) { loff[c2] = acc; acc += lcnt[c2]; }
    }
    __syncthreads();
    if (det) bkey[(size_t)b * DB + loff[bcls] + rank] = key;   // unique slot by construction
    if (tid < NC) {                                // unconditional -> self-initializing
        bcnt[(size_t)tid * NDB + b] = lcnt[tid];   // transposed [class][block]: coalesced
        boff[(size_t)tid * NDB + b] = loff[tid];
    }
}

// ---------------- helpers ----------------
__device__ __forceinline__ int to_px(float v) {
    float r = rintf(v * 831.0f);           // jnp.round = half-to-even
    r = fminf(fmaxf(r, 0.0f), 831.0f);     // clip AFTER round
    return (int)r;
}

// reference-exact IoU(winner W area aW, candidate C area aC) > T
__device__ __forceinline__ bool iou_gt_pre(const float4 W, float aW,
                                           const float4 C, float aC) {
    float x1 = fmaxf(W.x, C.x), y1 = fmaxf(W.y, C.y);
    float x2 = fminf(W.z, C.z), y2 = fminf(W.w, C.w);
    float inter = fmaxf(x2 - x1, 0.0f) * fmaxf(y2 - y1, 0.0f);
    float uni = aW + aC - inter;
    float iou = (uni > 0.0f) ? (inter / uni) : 0.0f;
    return iou > NMS_T_;
}

// bitonic compare-exchange via shfl_xor (stride <= 32), element index x
__device__ __forceinline__ u64 cex_shfl(u64 r, int x, int stride, int size) {
    u64 v = __shfl_xor(r, stride);
    bool asc   = (x & size) != 0;
    bool upper = (x & stride) != 0;
    bool keep_max = (!asc) != upper;     // XOR
    u64 mx = (r > v) ? r : v;
    u64 mn = (r > v) ? v : r;
    return keep_max ? mx : mn;
}

// ---------------- per-class: block-bucket filter -> hybrid sort -> walk -> draw ----------------
__global__ __launch_bounds__(1024) void select_draw_kernel(const u32* __restrict__ bcnt,
    const u32* __restrict__ boff, const u64* __restrict__ bkey,
    const float4* __restrict__ boxById, float* __restrict__ out)
{
    __shared__ u64    skey[SORTN];    // 16 KB
    __shared__ float4 sbox[SORTN];    // 32 KB
    __shared__ float4 selb[MAXB];
    __shared__ float  swa[MAXB];      // winner areas
    __shared__ float4 bbox[64];       // current walk batch (lane-local write)
    __shared__ float  barea[64];
    __shared__ u64    csA[16], csB[16], sfirst[16];
    __shared__ int    s_nsel, s_bad, s_cnt;

    const int c = blockIdx.x;
    const int t = threadIdx.x;
    const int w = t >> 6, l = t & 63;
    const int eA = (w << 7) + l, eB = eA + 64;   // wave w owns elements [128w,128w+128)

    if (t == 0) { s_bad = 0; s_nsel = 0; s_cnt = 0; }
    for (int i = t; i < SORTN; i += 1024) skey[i] = 0;
    __syncthreads();

    // ---- block-bucket filter: coalesced counts read + segment gather (R20-proven) ----
    for (int b = t; b < NDB; b += 1024) {
        u32 cb = bcnt[(size_t)c * NDB + b];
        if (cb) {
            u32 ob = boff[(size_t)c * NDB + b];
            int pos = atomicAdd(&s_cnt, (int)cb);
            const u64* src = bkey + (size_t)b * DB + ob;
            for (u32 i = 0; i < cb; ++i) {
                int d = pos + (int)i;
                if (d < SORTN) skey[d] = src[i];
            }
        }
    }
    __syncthreads();
    int count = s_cnt; if (count > SORTN) count = SORTN;

    u64 rA = skey[eA];
    u64 rB = skey[eB];

    // checksum of input multiset (XOR order-independent)
    {
        u64 x = rA ^ rB;
#pragma unroll
        for (int off = 32; off >= 1; off >>= 1) x ^= __shfl_xor(x, off);
        if (l == 0) csA[w] = x;
    }

    // ---- Phase A: in-register bitonic sort of each 128-chunk (no barriers) ----
#pragma unroll
    for (int size = 2; size <= 64; size <<= 1)
        for (int stride = size >> 1; stride >= 1; stride >>= 1) {
            rA = cex_shfl(rA, eA, stride, size);
            rB = cex_shfl(rB, eB, stride, size);
        }
    {   // size = 128: stride 64 is the in-lane register pair
        const int size = 128;
        bool asc = (eA & 128) != 0;
        u64 mx = (rA > rB) ? rA : rB, mn = (rA > rB) ? rB : rA;
        rA = asc ? mn : mx; rB = asc ? mx : mn;
        for (int stride = 32; stride >= 1; stride >>= 1) {
            rA = cex_shfl(rA, eA, stride, size);
            rB = cex_shfl(rB, eB, stride, size);
        }
    }

    // ---- Phase B: merge sizes 256..2048; only stride>=128 passes touch LDS ----
    for (int size = 256; size <= 2048; size <<= 1) {
        skey[eA] = rA; skey[eB] = rB;
        __syncthreads();
        for (int stride = size >> 1; stride >= 128; stride >>= 1) {
            int i = ((t & ~(stride - 1)) << 1) | (t & (stride - 1));
            int j = i | stride;
            bool asc = (i & size) != 0;
            u64 ki = skey[i], kj = skey[j];
            bool sw = asc ? (ki > kj) : (ki < kj);
            if (sw) { skey[i] = kj; skey[j] = ki; }
            __syncthreads();
        }
        rA = skey[eA]; rB = skey[eB];
        bool asc = (eA & size) != 0;   // stride 64: in-lane pair
        u64 mx = (rA > rB) ? rA : rB, mn = (rA > rB) ? rB : rA;
        rA = asc ? mn : mx; rB = asc ? mx : mn;
        for (int stride = 32; stride >= 1; stride >>= 1) {
            rA = cex_shfl(rA, eA, stride, size);
            rB = cex_shfl(rB, eB, stride, size);
        }
    }

    // ---- verify: descending order + XOR checksum ----
    {
        u64 x = rA ^ rB;
#pragma unroll
        for (int off = 32; off >= 1; off >>= 1) x ^= __shfl_xor(x, off);
        if (l == 0) { csB[w] = x; sfirst[w] = rA; }
        bool bad = false;
        u64 dA  = __shfl_down(rA, 1);
        u64 dB  = __shfl_down(rB, 1);
        u64 rB0 = __shfl(rB, 0);
        if (l < 63) { bad |= (rA < dA); bad |= (rB < dB); }
        if (l == 63) bad |= (rA < rB0);
        __syncthreads();
        if (l == 63 && w < 15) bad |= (rB < sfirst[w + 1]);
        if (t == 0) {
            u64 X0 = 0, X1 = 0;
            for (int i = 0; i < 16; ++i) { X0 ^= csA[i]; X1 ^= csB[i]; }
            if (X0 != X1) s_bad = 1;
        }
        if (bad) s_bad = 1;
        __syncthreads();
    }

    if (s_bad) {   // dormant fallback: re-filter + odd-even transposition
        for (int i = t; i < SORTN; i += 1024) skey[i] = 0;
        if (t == 0) s_cnt = 0;
        __syncthreads();
        for (int b = t; b < NDB; b += 1024) {
            u32 cb = bcnt[(size_t)c * NDB + b];
            if (cb) {
                u32 ob = boff[(size_t)c * NDB + b];
                int pos = atomicAdd(&s_cnt, (int)cb);
                const u64* src = bkey + (size_t)b * DB + ob;
                for (u32 i = 0; i < cb; ++i) {
                    int d = pos + (int)i;
                    if (d < SORTN) skey[d] = src[i];
                }
            }
        }
        __syncthreads();
        for (int ph = 0; ph < SORTN; ++ph) {
            int i = (t << 1) + (ph & 1);
            if (i + 1 < SORTN) {
                u64 a = skey[i], bb = skey[i + 1];
                if (a < bb) { skey[i] = bb; skey[i + 1] = a; }
            }
            __syncthreads();
        }
        rA = skey[eA]; rB = skey[eB];
    }

    // ---- gather boxes into sorted order (id = ~low32(key)) ----
    if (eA < count) sbox[eA] = boxById[~(u32)rA];
    if (eB < count) sbox[eB] = boxById[~(u32)rB];
    __syncthreads();

    // ---- wave-0 batched walk (exact sorted-greedy == reference argmax NMS) ----
    // picks use LDS broadcast of the batch (bbox/barea) instead of 5-shuffle chains
    if (t < 64) {
        const int lane = t;
        int nsel = 0;
        for (int p0 = 0; p0 < count && nsel < MAXB; p0 += 64) {
            int p = p0 + lane;
            bool have = (p < count);
            float4 C = sbox[have ? p : 0];
            float aC = (C.z - C.x) * (C.w - C.y);   // hoisted, bit-exact
            bbox[lane] = C; barea[lane] = aC;       // same-wave LDS RAW ordered

            // stage 1: suppressed by winners from previous batches (no early exit)
            bool sup = false;
#pragma unroll 4
            for (int ww = 0; ww < nsel; ++ww)
                sup |= iou_gt_pre(selb[ww], swa[ww], C, aC);

            u64 alive = __ballot(have && !sup);
            while (alive != 0ull && nsel < MAXB) {
                int i = __ffsll((long long)alive) - 1;   // lowest sorted index first
                float4 Wn = bbox[i]; float aWn = barea[i];   // broadcast read (bit-exact)
                if (lane == 0) { selb[nsel] = Wn; swa[nsel] = aWn; }
                ++nsel;
                u64 killed = __ballot(iou_gt_pre(Wn, aWn, C, aC));  // self-IoU=1 kills i
                alive &= ~killed;
            }
        }
        if (lane == 0) s_nsel = nsel;
    }
    __syncthreads();

    // ---- cooperative draw: float4 interior for horizontal edges, scalar verticals ----
    int nsel = s_nsel;
    int lane = t & 63;
    const float4 ones = make_float4(1.0f, 1.0f, 1.0f, 1.0f);
    for (int b = t >> 6; b < nsel; b += 16) {
        float4 B = selb[b];
        int r1 = to_px(B.x), c1 = to_px(B.y), r2 = to_px(B.z), c2 = to_px(B.w);

        // horizontal edges on rows r1, r2 over [c1, c2]
        int a0 = (c1 + 3) & ~3;          // first 16B-aligned col
        int a1 = (c2 + 1) & ~3;          // end of aligned region
        if (a0 < a1) {
            float4* row1 = (float4*)(out + r1 * IMG);
            float4* row2 = (float4*)(out + r2 * IMG);
            for (int v = (a0 >> 2) + lane; v < (a1 >> 2); v += 64) {
                row1[v] = ones; row2[v] = ones;
            }
            if (lane < 3) {               // head [c1,a0), tail [a1,c2] — each <= 3 px
                int hi = c1 + lane;
                if (hi < a0) { out[r1*IMG + hi] = 1.0f; out[r2*IMG + hi] = 1.0f; }
                int ti = a1 + lane;
                if (ti <= c2) { out[r1*IMG + ti] = 1.0f; out[r2*IMG + ti] = 1.0f; }
            }
        } else {                          // short run: all scalar
            for (int i = c1 + lane; i <= c2; i += 64) {
                out[r1*IMG + i] = 1.0f;
                out[r2*IMG + i] = 1.0f;
            }
        }

        // vertical edges (1.0f races benign)
        for (int i = r1 + lane; i <= r2; i += 64) {
            out[i*IMG + c1] = 1.0f;
            out[i*IMG + c2] = 1.0f;
        }
    }
}

extern "C" void kernel_launch(void* const* d_in, const int* in_sizes, int n_in,
                              void* d_out, int out_size, void* d_ws, size_t ws_size,
                              hipStream_t stream)
{
    const float* in      = (const float*)d_in[0];
    const float* anchors = (const float*)d_in[1];
    float* out           = (float*)d_out;

    char* ws = (char*)d_ws;
    size_t off = 0;
    float4* boxById = (float4*)(ws + off); off += (size_t)NBOX * sizeof(float4);      // 1,557,504
    u64*    bkey    = (u64*)(ws + off);    off += (size_t)NDB * DB * sizeof(u64);     //   779,264
    u32*    bcnt    = (u32*)(ws + off);    off += (size_t)NC * NDB * sizeof(u32);     //   243,520
    u32*    boff    = (u32*)(ws + off);    off += (size_t)NC * NDB * sizeof(u32);     //   243,520

    decode_kernel<<<NDB, DB, 0, stream>>>(in, anchors, bcnt, boff, bkey, boxById,
                                          (float4*)out);
    select_draw_kernel<<<NC, 1024, 0, stream>>>(bcnt, boff, bkey, boxById, out);
}

// Round 22
// 63.560 us; speedup vs baseline: 1.0618x; 1.0618x over previous
//
#pragma clang fp contract(off)
#include <hip/hip_runtime.h>
#include <math.h>

#define G       104
#define NBA     9
#define NC      80
#define NBOX    (G*G*NBA)      // 97344
#define CH      (5+NC)         // 85
#define DET_T_  0.02f
#define NMS_T_  0.3f
#define MAXB    50
#define SORTN   2048
#define IMG     832
#define DB      128            // decode boxes per block
#define NDB     ((NBOX + DB - 1) / DB)   // 761 decode blocks

typedef unsigned long long u64;
typedef unsigned int       u32;

__device__ __forceinline__ float sigmoidf_(float x) { return 1.0f / (1.0f + expf(-x)); }

// ---------------- decode: per-BLOCK deterministic class buckets (R20-proven) ----------------
// key = score_bits<<32 | ~id  (u64 desc == score desc, tie -> min original id)
__global__ __launch_bounds__(DB) void decode_kernel(const float* __restrict__ in,
        const float* __restrict__ anchors, u32* __restrict__ bcnt, u32* __restrict__ boff,
        u64* __restrict__ bkey, float4* __restrict__ boxById, float4* __restrict__ out4)
{
    __shared__ float lds[DB * CH];   // 43,520 B
    __shared__ u32   lcnt[NC], loff[NC];
    const int tid = threadIdx.x;
    const int b   = blockIdx.x;

    // canvas zero slice (stream-ordered before select_draw)
    {
        const int CZ = (IMG*IMG/4 + NDB - 1) / NDB;   // 228 float4 per block
        int zbase = b * CZ;
        for (int i = tid; i < CZ; i += DB) {
            int idx = zbase + i;
            if (idx < IMG*IMG/4) out4[idx] = make_float4(0, 0, 0, 0);
        }
    }

    const int base = b * (DB * CH);
    int nfl = NBOX * CH - base;
    if (nfl > DB * CH) nfl = DB * CH;

    int nv4 = nfl >> 2;
    const float4* gin4 = (const float4*)(in + base);
    for (int i = tid; i < nv4; i += DB) ((float4*)lds)[i] = gin4[i];
    for (int i = (nv4 << 2) + tid; i < nfl; i += DB) lds[i] = in[base + i];
    if (tid < NC) lcnt[tid] = 0;
    __syncthreads();

    int n = b * DB + tid;
    bool det = false; u64 key = 0; int bcls = 0; u32 rank = 0;

    if (n < NBOX) {
        const float* p = lds + tid * CH;

        float m = -INFINITY;
#pragma unroll
        for (int i = 0; i < NC; ++i) m = fmaxf(m, p[5 + i]);

        // sum in reference order + candidate bitmask (window -2e-6, 5x margin)
        float sum = 0.0f;
        u64 cm0 = 0, cm1 = 0;
#pragma unroll
        for (int i = 0; i < NC; ++i) {
            float d = p[5 + i] - m;
            sum += expf(d);
            u64 cand = (d >= -2.0e-6f) ? 1ull : 0ull;
            if (i < 64) cm0 |= cand << i;
            else        cm1 |= cand << (i - 64);
        }
        float obj = sigmoidf_(p[4]);

        // exact first-max over candidate classes only (ascending index)
        float best = -1.0f;
        while (cm0) {
            int i = __ffsll((long long)cm0) - 1; cm0 &= cm0 - 1;
            float e = expf(p[5 + i] - m);
            float s = obj * (e / sum);
            if (s > best) { best = s; bcls = i; }
        }
        while (cm1) {
            int i = __ffsll((long long)cm1) - 1 + 64; cm1 &= cm1 - 1;
            float e = expf(p[5 + i] - m);
            float s = obj * (e / sum);
            if (s > best) { best = s; bcls = i; }
        }

        if (best > DET_T_) {
            int a  = n % NBA;
            int t2 = n / NBA;
            int gx = t2 % G;
            int gy = t2 / G;
            float bx = (sigmoidf_(p[0]) + (float)gx) / (float)G;
            float by = (sigmoidf_(p[1]) + (float)gy) / (float)G;
            float bw = expf(p[2]) * anchors[2*a + 0] / (float)G;
            float bh = expf(p[3]) * anchors[2*a + 1] / (float)G;
            boxById[n] = make_float4(bx - bw / 2.0f, by - bh / 2.0f,
                                     bx + bw / 2.0f, by + bh / 2.0f);
            key = ((u64)__float_as_uint(best) << 32) | (u32)(~(u32)n);
            det = true;
        }
    }

    if (det) rank = atomicAdd(&lcnt[bcls], 1);    // rank within (block, class)
    __syncthreads();
    if (tid == 0) {                                // exclusive prefix over 80 classes
        u32 acc = 0;
        for (int c2 = 0; c2 < NC; ++c2) { loff[c2] = acc; acc += lcnt[c2]; }
    }
    __syncthreads();
    if (det) bkey[(size_t)b * DB + loff[bcls] + rank] = key;   // unique slot by construction
    if (tid < NC) {                                // unconditional -> self-initializing
        bcnt[(size_t)tid * NDB + b] = lcnt[tid];   // transposed [class][block]: coalesced
        boff[(size_t)tid * NDB + b] = loff[tid];
    }
}

// ---------------- helpers ----------------
__device__ __forceinline__ int to_px(float v) {
    float r = rintf(v * 831.0f);           // jnp.round = half-to-even
    r = fminf(fmaxf(r, 0.0f), 831.0f);     // clip AFTER round
    return (int)r;
}

// reference-exact IoU(winner W area aW, candidate C area aC) > T
__device__ __forceinline__ bool iou_gt_pre(const float4 W, float aW,
                                           const float4 C, float aC) {
    float x1 = fmaxf(W.x, C.x), y1 = fmaxf(W.y, C.y);
    float x2 = fminf(W.z, C.z), y2 = fminf(W.w, C.w);
    float inter = fmaxf(x2 - x1, 0.0f) * fmaxf(y2 - y1, 0.0f);
    float uni = aW + aC - inter;
    float iou = (uni > 0.0f) ? (inter / uni) : 0.0f;
    return iou > NMS_T_;
}

// bitonic compare-exchange via shfl_xor (stride <= 32), element index x
__device__ __forceinline__ u64 cex_shfl(u64 r, int x, int stride, int size) {
    u64 v = __shfl_xor(r, stride);
    bool asc   = (x & size) != 0;
    bool upper = (x & stride) != 0;
    bool keep_max = (!asc) != upper;     // XOR
    u64 mx = (r > v) ? r : v;
    u64 mn = (r > v) ? v : r;
    return keep_max ? mx : mn;
}

// ---------------- per-class: scan-filter -> hybrid sort -> walk -> draw ----------------
__global__ __launch_bounds__(1024) void select_draw_kernel(const u32* __restrict__ bcnt,
    const u32* __restrict__ boff, const u64* __restrict__ bkey,
    const float4* __restrict__ boxById, float* __restrict__ out)
{
    __shared__ u64    skey[SORTN];    // 16 KB
    __shared__ float4 sbox[SORTN];    // 32 KB
    __shared__ float4 selb[MAXB];
    __shared__ float  swa[MAXB];      // winner areas
    __shared__ float4 bbox[64];       // current walk batch (lane-local write)
    __shared__ float  barea[64];
    __shared__ u32    woff[17];       // wave offsets for the count scan
    __shared__ int    s_nsel;

    const int c = blockIdx.x;
    const int t = threadIdx.x;
    const int w = t >> 6, l = t & 63;
    const int eA = (w << 7) + l, eB = eA + 64;   // wave w owns elements [128w,128w+128)

    if (t == 0) s_nsel = 0;

    // ---- deterministic filter: prefix-scan the per-block counts, direct placement ----
    // (same key multiset as R20's atomic filter -> identical sorted sequence, keys unique)
    u32 myc = (t < NDB) ? bcnt[(size_t)c * NDB + t] : 0u;
    u32 inc = myc;
#pragma unroll
    for (int off = 1; off < 64; off <<= 1) {       // wave-inclusive scan
        u32 v = __shfl_up(inc, off);
        if (l >= off) inc += v;
    }
    if (l == 63) woff[w] = inc;                    // wave total
    __syncthreads();
    if (t == 0) {
        u32 acc = 0;
        for (int i = 0; i < 16; ++i) { u32 v = woff[i]; woff[i] = acc; acc += v; }
        woff[16] = acc;
    }
    __syncthreads();
    u32 excl  = woff[w] + inc - myc;               // exclusive global offset
    int total = (int)woff[16];
    int count = (total > SORTN) ? SORTN : total;

    if (myc) {                                     // t < NDB implied (myc==0 otherwise)
        u32 ob = boff[(size_t)c * NDB + t];
        const u64* src = bkey + (size_t)t * DB + ob;
        for (u32 i = 0; i < myc; ++i) {
            u32 d = excl + i;
            if (d < SORTN) skey[d] = src[i];
        }
    }
    for (int i = count + t; i < SORTN; i += 1024) skey[i] = 0;   // pads sink to end
    __syncthreads();

    u64 rA = skey[eA];
    u64 rB = skey[eB];

    // ---- Phase A: in-register bitonic sort of each 128-chunk (no barriers) ----
#pragma unroll
    for (int size = 2; size <= 64; size <<= 1)
        for (int stride = size >> 1; stride >= 1; stride >>= 1) {
            rA = cex_shfl(rA, eA, stride, size);
            rB = cex_shfl(rB, eB, stride, size);
        }
    {   // size = 128: stride 64 is the in-lane register pair
        const int size = 128;
        bool asc = (eA & 128) != 0;
        u64 mx = (rA > rB) ? rA : rB, mn = (rA > rB) ? rB : rA;
        rA = asc ? mn : mx; rB = asc ? mx : mn;
        for (int stride = 32; stride >= 1; stride >>= 1) {
            rA = cex_shfl(rA, eA, stride, size);
            rB = cex_shfl(rB, eB, stride, size);
        }
    }

    // ---- Phase B: merge sizes 256..2048; only stride>=128 passes touch LDS ----
    for (int size = 256; size <= 2048; size <<= 1) {
        skey[eA] = rA; skey[eB] = rB;
        __syncthreads();
        for (int stride = size >> 1; stride >= 128; stride >>= 1) {
            int i = ((t & ~(stride - 1)) << 1) | (t & (stride - 1));
            int j = i | stride;
            bool asc = (i & size) != 0;
            u64 ki = skey[i], kj = skey[j];
            bool sw = asc ? (ki > kj) : (ki < kj);
            if (sw) { skey[i] = kj; skey[j] = ki; }
            __syncthreads();
        }
        rA = skey[eA]; rB = skey[eB];
        bool asc = (eA & size) != 0;   // stride 64: in-lane pair
        u64 mx = (rA > rB) ? rA : rB, mn = (rA > rB) ? rB : rA;
        rA = asc ? mn : mx; rB = asc ? mx : mn;
        for (int stride = 32; stride >= 1; stride >>= 1) {
            rA = cex_shfl(rA, eA, stride, size);
            rB = cex_shfl(rB, eB, stride, size);
        }
    }
    // (verify/fallback removed: sort code bit-frozen and passing since R8;
    //  harness absmax-validates every run)

    // ---- gather boxes into sorted order (id = ~low32(key)) ----
    if (eA < count) sbox[eA] = boxById[~(u32)rA];
    if (eB < count) sbox[eB] = boxById[~(u32)rB];
    __syncthreads();

    // ---- wave-0 batched walk (exact sorted-greedy == reference argmax NMS) ----
    if (t < 64) {
        const int lane = t;
        int nsel = 0;
        for (int p0 = 0; p0 < count && nsel < MAXB; p0 += 64) {
            int p = p0 + lane;
            bool have = (p < count);
            float4 C = sbox[have ? p : 0];
            float aC = (C.z - C.x) * (C.w - C.y);   // hoisted, bit-exact
            bbox[lane] = C; barea[lane] = aC;       // same-wave LDS RAW ordered

            // stage 1: suppressed by winners from previous batches (no early exit)
            bool sup = false;
#pragma unroll 4
            for (int ww = 0; ww < nsel; ++ww)
                sup |= iou_gt_pre(selb[ww], swa[ww], C, aC);

            u64 alive = __ballot(have && !sup);
            while (alive != 0ull && nsel < MAXB) {
                int i = __ffsll((long long)alive) - 1;   // lowest sorted index first
                float4 Wn = bbox[i]; float aWn = barea[i];   // broadcast read (bit-exact)
                if (lane == 0) { selb[nsel] = Wn; swa[nsel] = aWn; }
                ++nsel;
                u64 killed = __ballot(iou_gt_pre(Wn, aWn, C, aC));  // self-IoU=1 kills i
                alive &= ~killed;
            }
        }
        if (lane == 0) s_nsel = nsel;
    }
    __syncthreads();

    // ---- cooperative draw: float4 interior for horizontal edges, scalar verticals ----
    int nsel = s_nsel;
    int lane = t & 63;
    const float4 ones = make_float4(1.0f, 1.0f, 1.0f, 1.0f);
    for (int b = t >> 6; b < nsel; b += 16) {
        float4 B = selb[b];
        int r1 = to_px(B.x), c1 = to_px(B.y), r2 = to_px(B.z), c2 = to_px(B.w);

        // horizontal edges on rows r1, r2 over [c1, c2]
        int a0 = (c1 + 3) & ~3;          // first 16B-aligned col
        int a1 = (c2 + 1) & ~3;          // end of aligned region
        if (a0 < a1) {
            float4* row1 = (float4*)(out + r1 * IMG);
            float4* row2 = (float4*)(out + r2 * IMG);
            for (int v = (a0 >> 2) + lane; v < (a1 >> 2); v += 64) {
                row1[v] = ones; row2[v] = ones;
            }
            if (lane < 3) {               // head [c1,a0), tail [a1,c2] — each <= 3 px
                int hi = c1 + lane;
                if (hi < a0) { out[r1*IMG + hi] = 1.0f; out[r2*IMG + hi] = 1.0f; }
                int ti = a1 + lane;
                if (ti <= c2) { out[r1*IMG + ti] = 1.0f; out[r2*IMG + ti] = 1.0f; }
            }
        } else {                          // short run: all scalar
            for (int i = c1 + lane; i <= c2; i += 64) {
                out[r1*IMG + i] = 1.0f;
                out[r2*IMG + i] = 1.0f;
            }
        }

        // vertical edges (1.0f races benign)
        for (int i = r1 + lane; i <= r2; i += 64) {
            out[i*IMG + c1] = 1.0f;
            out[i*IMG + c2] = 1.0f;
        }
    }
}

extern "C" void kernel_launch(void* const* d_in, const int* in_sizes, int n_in,
                              void* d_out, int out_size, void* d_ws, size_t ws_size,
                              hipStream_t stream)
{
    const float* in      = (const float*)d_in[0];
    const float* anchors = (const float*)d_in[1];
    float* out           = (float*)d_out;

    char* ws = (char*)d_ws;
    size_t off = 0;
    float4* boxById = (float4*)(ws + off); off += (size_t)NBOX * sizeof(float4);      // 1,557,504
    u64*    bkey    = (u64*)(ws + off);    off += (size_t)NDB * DB * sizeof(u64);     //   779,264
    u32*    bcnt    = (u32*)(ws + off);    off += (size_t)NC * NDB * sizeof(u32);     //   243,520
    u32*    boff    = (u32*)(ws + off);    off += (size_t)NC * NDB * sizeof(u32);     //   243,520

    decode_kernel<<<NDB, DB, 0, stream>>>(in, anchors, bcnt, boff, bkey, boxById,
                                          (float4*)out);
    select_draw_kernel<<<NC, 1024, 0, stream>>>(bcnt, boff, bkey, boxById, out);
}